// Round 1
// baseline (490.954 us; speedup 1.0000x reference)
//
#include <hip/hip_runtime.h>
#include <math.h>

#define GAMMA 0.25f
constexpr int B = 8, Q = 64, N = 8192, K = 512, C = 256;

// One thread per (b,n). Computes:
//   rec  = logsumexp_c(qp[b,:,n]) - qp[b,t,n]
//   vq   = 1.25 * (||ze[b,:,n]||^2 + min_k (||emb[k]||^2 - 2 ze.emb[k]))
// block-reduces and atomicAdds into out[0].
__global__ __launch_bounds__(256) void vq_main(
    const float* __restrict__ ze,
    const float* __restrict__ emb,
    const float* __restrict__ qp,
    const int*   __restrict__ tgt,
    float* __restrict__ out)
{
    // --- per-block: precompute e2[k] = ||emb[k]||^2 into LDS (512 floats) ---
    __shared__ float e2s[K];
    for (int k = threadIdx.x; k < K; k += blockDim.x) {
        const float* ek = emb + k * Q;
        float s0 = 0.f, s1 = 0.f, s2 = 0.f, s3 = 0.f;
        #pragma unroll
        for (int q = 0; q < Q; q += 4) {
            s0 = fmaf(ek[q + 0], ek[q + 0], s0);
            s1 = fmaf(ek[q + 1], ek[q + 1], s1);
            s2 = fmaf(ek[q + 2], ek[q + 2], s2);
            s3 = fmaf(ek[q + 3], ek[q + 3], s3);
        }
        e2s[k] = (s0 + s1) + (s2 + s3);
    }
    __syncthreads();

    const int idx = blockIdx.x * blockDim.x + threadIdx.x;   // 0..B*N-1
    const int b = idx >> 13;          // idx / N
    const int n = idx & (N - 1);      // idx % N

    // ---------------- CE: online log-softmax over C=256 ----------------
    const float* qpb = qp + (size_t)b * C * N + n;
    float m = -INFINITY, s = 0.f;
    #pragma unroll 4
    for (int c = 0; c < C; ++c) {
        float x = qpb[(size_t)c * N];
        float mnew = fmaxf(m, x);
        // branch-free online update; first iter: exp(-inf)=0 handles init
        s = s * __expf(m - mnew) + __expf(x - mnew);
        m = mnew;
    }
    const int t = tgt[b * N + n];
    const float xt = qpb[(size_t)t * N];
    const float rec = m + __logf(s) - xt;

    // ---------------- VQ: min_k ||z - e_k||^2 via expansion ----------------
    const float* zeb = ze + (size_t)b * Q * N + n;
    float z[Q];
    float z0 = 0.f, z1 = 0.f, z2 = 0.f, z3 = 0.f;
    #pragma unroll
    for (int q = 0; q < Q; q += 4) {
        z[q + 0] = zeb[(size_t)(q + 0) * N];
        z[q + 1] = zeb[(size_t)(q + 1) * N];
        z[q + 2] = zeb[(size_t)(q + 2) * N];
        z[q + 3] = zeb[(size_t)(q + 3) * N];
        z0 = fmaf(z[q + 0], z[q + 0], z0);
        z1 = fmaf(z[q + 1], z[q + 1], z1);
        z2 = fmaf(z[q + 2], z[q + 2], z2);
        z3 = fmaf(z[q + 3], z[q + 3], z3);
    }
    const float ze2 = (z0 + z1) + (z2 + z3);

    float best = INFINITY;
    for (int k = 0; k < K; ++k) {
        const float* ek = emb + k * Q;   // wave-uniform address -> s_load
        float d0 = 0.f, d1 = 0.f, d2 = 0.f, d3 = 0.f;
        #pragma unroll
        for (int q = 0; q < Q; q += 4) {
            d0 = fmaf(z[q + 0], ek[q + 0], d0);
            d1 = fmaf(z[q + 1], ek[q + 1], d1);
            d2 = fmaf(z[q + 2], ek[q + 2], d2);
            d3 = fmaf(z[q + 3], ek[q + 3], d3);
        }
        const float score = e2s[k] - 2.f * ((d0 + d1) + (d2 + d3));
        best = fminf(best, score);
    }

    float loss = rec + (1.f + GAMMA) * (ze2 + best);

    // ---------------- reduction: wave (64) -> block -> atomic ----------------
    #pragma unroll
    for (int off = 32; off > 0; off >>= 1)
        loss += __shfl_down(loss, off, 64);

    __shared__ float red[4];
    const int lane = threadIdx.x & 63;
    const int w = threadIdx.x >> 6;
    if (lane == 0) red[w] = loss;
    __syncthreads();
    if (threadIdx.x == 0)
        atomicAdd(out, (red[0] + red[1]) + (red[2] + red[3]));
}

extern "C" void kernel_launch(void* const* d_in, const int* in_sizes, int n_in,
                              void* d_out, int out_size, void* d_ws, size_t ws_size,
                              hipStream_t stream) {
    const float* ze  = (const float*)d_in[0];
    const float* emb = (const float*)d_in[1];
    const float* qp  = (const float*)d_in[2];
    const int*   tgt = (const int*)d_in[3];
    float* out = (float*)d_out;

    hipMemsetAsync(out, 0, sizeof(float), stream);  // d_out is re-poisoned each call

    const int total = B * N;          // 65536
    const int block = 256;
    vq_main<<<total / block, block, 0, stream>>>(ze, emb, qp, tgt, out);
}

// Round 2
// 350.640 us; speedup vs baseline: 1.4002x; 1.4002x over previous
//
#include <hip/hip_runtime.h>
#include <math.h>

#define GAMMA 0.25f
constexpr int B = 8, Q = 64, NN = 8192, K = 512, C = 256;

// Block = 256 threads = 4 waves, covering 64 consecutive (b,n) items (lane = item).
// Wave w handles codebook quarter k in [128w,128w+128) and class quarter
// c in [64w, 64w+64). Partial results combined via LDS; wave 0 finishes.
__global__ __launch_bounds__(256, 4) void vq_main(
    const float* __restrict__ ze,
    const float* __restrict__ emb,
    const float* __restrict__ qp,
    const int*   __restrict__ tgt,
    float* __restrict__ out)
{
    __shared__ float e2s[K];        // ||emb_k||^2
    __shared__ float bestL[4][64];  // per-wave VQ partial min
    __shared__ float sumL[4][64];   // per-wave CE partial sum(exp)

    // --- e2[k] = ||emb[k]||^2 (2 rows per thread) ---
    for (int k = threadIdx.x; k < K; k += 256) {
        const float* ek = emb + k * Q;
        float s0 = 0.f, s1 = 0.f, s2 = 0.f, s3 = 0.f;
        #pragma unroll
        for (int q = 0; q < Q; q += 4) {
            s0 = fmaf(ek[q + 0], ek[q + 0], s0);
            s1 = fmaf(ek[q + 1], ek[q + 1], s1);
            s2 = fmaf(ek[q + 2], ek[q + 2], s2);
            s3 = fmaf(ek[q + 3], ek[q + 3], s3);
        }
        e2s[k] = (s0 + s1) + (s2 + s3);
    }
    __syncthreads();

    const int lane = threadIdx.x & 63;
    const int w    = threadIdx.x >> 6;
    const int idx  = blockIdx.x * 64 + lane;   // flat (b,n), 64-aligned so b uniform per block
    const int b    = idx >> 13;                // / NN
    const int n    = idx & (NN - 1);

    // --- load this item's z vector (coalesced across lanes per q) ---
    const float* zeb = ze + (size_t)b * Q * NN + n;
    float z[Q];
    #pragma unroll
    for (int q = 0; q < Q; ++q) z[q] = zeb[(size_t)q * NN];

    // --- VQ: min over my 128 codewords of (e2 - 2 z.e) ---
    float best = INFINITY;
    const float* ek = emb + (w * 128) * Q;     // wave-uniform -> s_load
    for (int k = 0; k < 128; ++k, ek += Q) {
        float d0 = 0.f, d1 = 0.f, d2 = 0.f, d3 = 0.f;
        #pragma unroll
        for (int q = 0; q < Q; q += 4) {
            d0 = fmaf(z[q + 0], ek[q + 0], d0);
            d1 = fmaf(z[q + 1], ek[q + 1], d1);
            d2 = fmaf(z[q + 2], ek[q + 2], d2);
            d3 = fmaf(z[q + 3], ek[q + 3], d3);
        }
        const float d = e2s[w * 128 + k] - 2.f * ((d0 + d1) + (d2 + d3));
        best = fminf(best, d);
    }

    // --- CE partial: sum(exp(x)) over my 64 classes (no max-sub; |x|<~6) ---
    const float* qpb = qp + (size_t)b * C * NN + n;
    float s0 = 0.f, s1 = 0.f, s2 = 0.f, s3 = 0.f;
    #pragma unroll 4
    for (int c = w * 64; c < w * 64 + 64; c += 4) {
        s0 += __expf(qpb[(size_t)(c + 0) * NN]);
        s1 += __expf(qpb[(size_t)(c + 1) * NN]);
        s2 += __expf(qpb[(size_t)(c + 2) * NN]);
        s3 += __expf(qpb[(size_t)(c + 3) * NN]);
    }

    bestL[w][lane] = best;
    sumL[w][lane]  = (s0 + s1) + (s2 + s3);
    __syncthreads();

    // --- wave 0 finishes: combine, ze2, target gather, reduce, atomic ---
    if (w == 0) {
        const float bmin = fminf(fminf(bestL[0][lane], bestL[1][lane]),
                                 fminf(bestL[2][lane], bestL[3][lane]));
        const float ssum = (sumL[0][lane] + sumL[1][lane]) +
                           (sumL[2][lane] + sumL[3][lane]);

        float z0 = 0.f, z1 = 0.f, z2 = 0.f, z3 = 0.f;
        #pragma unroll
        for (int q = 0; q < Q; q += 4) {
            z0 = fmaf(z[q + 0], z[q + 0], z0);
            z1 = fmaf(z[q + 1], z[q + 1], z1);
            z2 = fmaf(z[q + 2], z[q + 2], z2);
            z3 = fmaf(z[q + 3], z[q + 3], z3);
        }
        const float ze2 = (z0 + z1) + (z2 + z3);

        const int   t  = tgt[idx];
        const float xt = qpb[(size_t)t * NN];

        float loss = (__logf(ssum) - xt) + (1.f + GAMMA) * (ze2 + bmin);

        #pragma unroll
        for (int off = 32; off > 0; off >>= 1)
            loss += __shfl_down(loss, off, 64);
        if (lane == 0) atomicAdd(out, loss);
    }
}

extern "C" void kernel_launch(void* const* d_in, const int* in_sizes, int n_in,
                              void* d_out, int out_size, void* d_ws, size_t ws_size,
                              hipStream_t stream) {
    const float* ze  = (const float*)d_in[0];
    const float* emb = (const float*)d_in[1];
    const float* qp  = (const float*)d_in[2];
    const int*   tgt = (const int*)d_in[3];
    float* out = (float*)d_out;

    hipMemsetAsync(out, 0, sizeof(float), stream);

    const int blocks = (B * NN) / 64;   // 1024 blocks x 256 threads
    vq_main<<<blocks, 256, 0, stream>>>(ze, emb, qp, tgt, out);
}

// Round 4
// 163.351 us; speedup vs baseline: 3.0055x; 2.1465x over previous
//
#include <hip/hip_runtime.h>
#include <math.h>

#define GAMMA 0.25f
constexpr int B_ = 8, Q_ = 64, N_ = 8192, K_ = 512, C_ = 256;

typedef __attribute__((ext_vector_type(8))) short bf16x8;
typedef __attribute__((ext_vector_type(4))) short short4v;
typedef __attribute__((ext_vector_type(4))) float f32x4;

static __device__ inline short f2bf(float x) {   // RNE float->bf16 bits
    union { float f; unsigned u; } v; v.f = x;
    unsigned r = (v.u + 0x7fffu + ((v.u >> 16) & 1u)) >> 16;
    return (short)r;
}
static __device__ inline float bf2f(short h) {
    union { unsigned u; float f; } v; v.u = ((unsigned)(unsigned short)h) << 16;
    return v.f;
}

// ---------------------------------------------------------------------------
// VQ kernel: per block = 128 items (4 waves x 2 tiles of 16).
// D[item,k] = <z_item, e_k> via mfma_f32_16x16x32_bf16; loss += 1.25*(ze2+min_k(e2-2D)).
// emb staged to LDS as bf16 in two 256-row chunks, row stride 72 bf16 (144B:
// dword base = 36*row ≡ 4*row mod 32 -> even bank spread for ds_read_b128).
// ---------------------------------------------------------------------------
__global__ __launch_bounds__(256, 2) void vq_kernel(const float* __restrict__ ze,
                                                    const float* __restrict__ emb,
                                                    float* __restrict__ out)
{
    constexpr int STR = 72;                 // bf16 elems per LDS row (64 + 8 pad)
    __shared__ short embL[256 * STR];       // 36,864 B: one 256-codeword chunk
    __shared__ float e2s[512];              // ||e_k||^2 (from bf16, consistent w/ dot)

    const int tid  = threadIdx.x;
    const int lane = tid & 63;
    const int w    = tid >> 6;
    const int n16  = lane & 15;             // MFMA row/col lane index
    const int quad = lane >> 4;

    // ---- A fragments for this wave's two 16-item tiles + exact fp32 sum(z^2) ----
    const int ib0 = blockIdx.x * 128;       // first flat item (b,n); 128-aligned => b uniform
    const int b   = ib0 >> 13;
    const int n0  = ib0 & (N_ - 1);
    const float* zb = ze + (size_t)b * Q_ * N_;

    bf16x8 afrag[2][2];
    float zsq = 0.f;
    #pragma unroll
    for (int u = 0; u < 2; ++u) {
        const int nn = n0 + u * 64 + w * 16 + n16;
        #pragma unroll
        for (int s = 0; s < 2; ++s) {
            #pragma unroll
            for (int j = 0; j < 8; ++j) {
                const int q = s * 32 + quad * 8 + j;   // A[m=n16][k=q]
                const float x = zb[(size_t)q * N_ + nn];
                zsq = fmaf(x, x, zsq);
                afrag[u][s][j] = f2bf(x);
            }
        }
    }

    f32x4 best0 = {1e30f, 1e30f, 1e30f, 1e30f};
    f32x4 best1 = best0;

    for (int c = 0; c < 2; ++c) {
        __syncthreads();                     // all waves done with previous chunk
        // ---- stage 256 emb rows (fp32 -> bf16) into LDS, coalesced float4 ----
        {
            const float4* src = (const float4*)(emb + c * 256 * Q_);
            #pragma unroll
            for (int i = tid; i < 4096; i += 256) {   // 4096 float4 groups
                const int row = i >> 4;               // 16 groups per 64-elem row
                const int col = (i & 15) * 4;
                const float4 v = src[i];
                *(short4v*)(embL + row * STR + col) =
                    (short4v){f2bf(v.x), f2bf(v.y), f2bf(v.z), f2bf(v.w)};
            }
        }
        __syncthreads();
        // ---- e2 for this chunk, from the staged bf16 (one row per thread) ----
        {
            const bf16x8* row = (const bf16x8*)(embL + tid * STR);  // 144B-aligned
            float s = 0.f;
            #pragma unroll
            for (int k = 0; k < 8; ++k) {
                const bf16x8 v = row[k];
                #pragma unroll
                for (int j = 0; j < 8; ++j) { const float x = bf2f(v[j]); s = fmaf(x, x, s); }
            }
            e2s[c * 256 + tid] = s;
        }
        __syncthreads();

        // ---- 16 codeword-tiles of 16; fold min out of the accumulators ----
        for (int t = 0; t < 16; ++t) {
            const int rt = t * 16 + n16;    // LDS row: codeword n16 of tile t
            const bf16x8 bf0 = *(const bf16x8*)(embL + rt * STR + quad * 8);        // k=0..31
            const bf16x8 bf1 = *(const bf16x8*)(embL + rt * STR + 32 + quad * 8);   // k=32..63
            const float e2v = e2s[c * 256 + t * 16 + n16];

            const f32x4 zero = {0.f, 0.f, 0.f, 0.f};
            f32x4 acc0 = __builtin_amdgcn_mfma_f32_16x16x32_bf16(afrag[0][0], bf0, zero, 0, 0, 0);
            acc0       = __builtin_amdgcn_mfma_f32_16x16x32_bf16(afrag[0][1], bf1, acc0, 0, 0, 0);
            f32x4 acc1 = __builtin_amdgcn_mfma_f32_16x16x32_bf16(afrag[1][0], bf0, zero, 0, 0, 0);
            acc1       = __builtin_amdgcn_mfma_f32_16x16x32_bf16(afrag[1][1], bf1, acc1, 0, 0, 0);
            #pragma unroll
            for (int r = 0; r < 4; ++r) {
                best0[r] = fminf(best0[r], e2v - 2.f * acc0[r]);
                best1[r] = fminf(best1[r], e2v - 2.f * acc1[r]);
            }
        }
    }

    // ---- min over the 16 codeword lanes (xor butterfly in low 4 lane bits) ----
    #pragma unroll
    for (int m = 1; m < 16; m <<= 1) {
        #pragma unroll
        for (int r = 0; r < 4; ++r) {
            best0[r] = fminf(best0[r], __shfl_xor(best0[r], m, 64));
            best1[r] = fminf(best1[r], __shfl_xor(best1[r], m, 64));
        }
    }

    float val = 1.25f * zsq;                 // sum z^2 over this lane's A elements (exact)
    if (n16 == 0) {                          // one lane per item-row group adds the mins
        float s = 0.f;
        #pragma unroll
        for (int r = 0; r < 4; ++r) s += best0[r] + best1[r];
        val += 1.25f * s;
    }
    #pragma unroll
    for (int off = 32; off > 0; off >>= 1) val += __shfl_down(val, off, 64);
    if (lane == 0) atomicAdd(out, val);
}

// ---------------------------------------------------------------------------
// CE kernel: block = 64 items x 4 class-quarters; no-max sum(exp) (|x|<~6).
// ---------------------------------------------------------------------------
__global__ __launch_bounds__(256, 4) void ce_kernel(const float* __restrict__ qp,
                                                    const int* __restrict__ tgt,
                                                    float* __restrict__ out)
{
    __shared__ float part[4][64];
    const int lane = threadIdx.x & 63;
    const int w    = threadIdx.x >> 6;
    const int idx  = blockIdx.x * 64 + lane;
    const int b    = idx >> 13;
    const int n    = idx & (N_ - 1);
    const float* qpb = qp + (size_t)b * C_ * N_ + n;

    float s0 = 0.f, s1 = 0.f, s2 = 0.f, s3 = 0.f;
    #pragma unroll 8
    for (int c = w * 64; c < w * 64 + 64; c += 4) {
        s0 += __expf(qpb[(size_t)(c + 0) * N_]);
        s1 += __expf(qpb[(size_t)(c + 1) * N_]);
        s2 += __expf(qpb[(size_t)(c + 2) * N_]);
        s3 += __expf(qpb[(size_t)(c + 3) * N_]);
    }
    part[w][lane] = (s0 + s1) + (s2 + s3);
    __syncthreads();

    if (w == 0) {
        const float ssum = (part[0][lane] + part[1][lane]) +
                           (part[2][lane] + part[3][lane]);
        const float xt = qpb[(size_t)tgt[idx] * N_];
        float loss = __logf(ssum) - xt;
        #pragma unroll
        for (int off = 32; off > 0; off >>= 1) loss += __shfl_down(loss, off, 64);
        if (lane == 0) atomicAdd(out, loss);
    }
}

extern "C" void kernel_launch(void* const* d_in, const int* in_sizes, int n_in,
                              void* d_out, int out_size, void* d_ws, size_t ws_size,
                              hipStream_t stream) {
    const float* ze  = (const float*)d_in[0];
    const float* emb = (const float*)d_in[1];
    const float* qp  = (const float*)d_in[2];
    const int*   tgt = (const int*)d_in[3];
    float* out = (float*)d_out;

    hipMemsetAsync(out, 0, sizeof(float), stream);

    ce_kernel<<<(B_ * N_) / 64, 256, 0, stream>>>(qp, tgt, out);
    vq_kernel<<<(B_ * N_) / 128, 256, 0, stream>>>(ze, emb, out);
}